// Round 4
// baseline (158.465 us; speedup 1.0000x reference)
//
#include <hip/hip_runtime.h>
#include <hip/hip_bf16.h>

#define IMG 128
#define NPIX (IMG * IMG)
#define NT 64
#define LS 129  // padded LDS row stride: 129 % 32 == 1 -> adjacent rows in adjacent banks

// thr^2 where thr = round_half_even(linspace(2, 90, 64))
__device__ __constant__ int c_thr2[NT] = {
    4,    9,    25,   36,   64,   81,   100,  144,  169,  225,  256,  289,
    361,  400,  484,  529,  576,  676,  729,  841,  900,  961,  1089, 1156,
    1296, 1369, 1444, 1600, 1681, 1849, 1936, 2025, 2209, 2304, 2401, 2601,
    2704, 2916, 3025, 3136, 3364, 3481, 3721, 3844, 3969, 4225, 4356, 4624,
    4761, 4900, 5184, 5329, 5625, 5776, 5929, 6241, 6400, 6724, 6889, 7056,
    7396, 7569, 7921, 8100};

// One block per batch element. For each of 3 channels: 2D FFT of d = pred - gt
// (radix-2 DIF, natural in / bit-reversed out) in LDS, radial energy histogram
// accumulated in LDS. Then prefix-sum + PSNR -> d_out. No workspace, no global
// atomics: the ONLY global writes are the 64 output floats per block.
__global__ __launch_bounds__(1024) void fused_psnr_kernel(const float* __restrict__ pred,
                                                          const float* __restrict__ gt,
                                                          float* __restrict__ out) {
    __shared__ float s_re[IMG * LS];  // 64.5 KiB
    __shared__ float s_im[IMG * LS];  // 64.5 KiB
    __shared__ float s_twc[64];
    __shared__ float s_tws[64];
    __shared__ float s_hist[NT];

    const int tid = threadIdx.x;
    const int b = blockIdx.x;

    if (tid < 64) {
        float ang = -6.2831853071795864769f * (float)tid * (1.0f / 128.0f);
        float sv, cv;
        sincosf(ang, &sv, &cv);
        s_twc[tid] = cv;
        s_tws[tid] = sv;
        s_hist[tid] = 0.0f;
    }

    for (int ch = 0; ch < 3; ++ch) {
        const size_t base = ((size_t)b * 3 + ch) * NPIX;

        // load d = pred - gt (coalesced), im = 0
        for (int i = tid; i < NPIX; i += 1024) {
            const int r = i >> 7, c = i & 127;
            s_re[r * LS + c] = pred[base + i] - gt[base + i];
            s_im[r * LS + c] = 0.0f;
        }
        __syncthreads();  // also covers the tid<64 init on ch==0

        // ---- row FFTs: lanes span ROWS (stride LS -> 2-way, conflict-free) ----
        for (int s = 6; s >= 0; --s) {
            const int m = 1 << s;
            for (int id = tid; id < 8192; id += 1024) {
                const int row = id & 127;  // consecutive lanes -> consecutive rows
                const int bfl = id >> 7;   // wave-uniform
                const int j = bfl & (m - 1);
                const int g = bfl >> s;
                const int i1 = (g << (s + 1)) + j;
                const int a1 = row * LS + i1;
                const int a2 = a1 + m;
                const int twi = j << (6 - s);
                float ur = s_re[a1], ui = s_im[a1];
                float vr = s_re[a2], vi = s_im[a2];
                float wc = s_twc[twi], ws = s_tws[twi];
                float dr = ur - vr, di = ui - vi;
                s_re[a1] = ur + vr;
                s_im[a1] = ui + vi;
                s_re[a2] = dr * wc - di * ws;
                s_im[a2] = dr * ws + di * wc;
            }
            __syncthreads();
        }

        // ---- column FFTs: lanes span COLS (conflict-free) ----
        for (int s = 6; s >= 0; --s) {
            const int m = 1 << s;
            for (int id = tid; id < 8192; id += 1024) {
                const int col = id & 127;  // consecutive lanes -> consecutive cols
                const int bfl = id >> 7;
                const int j = bfl & (m - 1);
                const int g = bfl >> s;
                const int i1 = (g << (s + 1)) + j;
                const int a1 = i1 * LS + col;
                const int a2 = a1 + m * LS;
                const int twi = j << (6 - s);
                float ur = s_re[a1], ui = s_im[a1];
                float vr = s_re[a2], vi = s_im[a2];
                float wc = s_twc[twi], ws = s_tws[twi];
                float dr = ur - vr, di = ui - vi;
                s_re[a1] = ur + vr;
                s_im[a1] = ui + vi;
                s_re[a2] = dr * wc - di * ws;
                s_im[a2] = dr * ws + di * wc;
            }
            __syncthreads();
        }

        // ---- energy -> radial histogram (stored (r,c) holds freq (rev7(r), rev7(c))) ----
        for (int i = tid; i < NPIX; i += 1024) {
            const int r = i >> 7, c = i & 127;
            int fy = (int)(__brev((unsigned)r) >> 25);
            int fx = (int)(__brev((unsigned)c) >> 25);
            fy = (fy < 64) ? fy : fy - 128;
            fx = (fx < 64) ? fx : fx - 128;
            const int r2 = fy * fy + fx * fx;
            if (r2 <= 8100) {
                const int a = r * LS + c;
                const float e = s_re[a] * s_re[a] + s_im[a] * s_im[a];
                int lo = 0, hi = 63;  // smallest t with thr2[t] >= r2
                while (lo < hi) {
                    int mid = (lo + hi) >> 1;
                    if (c_thr2[mid] >= r2) hi = mid;
                    else lo = mid + 1;
                }
                atomicAdd(&s_hist[lo], e);  // block-local LDS atomic
            }
        }
        __syncthreads();  // s_hist complete; s_re/s_im reusable for next channel
    }

    // ---- inclusive prefix over bins, PSNR ----
    if (tid < 64) {
        float cum = 0.0f;
        for (int j = 0; j <= tid; ++j) cum += s_hist[j];
        out[b * NT + tid] = 84.2883987849f - 10.0f * log10f(cum);  // 20*log10(16384) - 10*log10(cum)
    }
}

extern "C" void kernel_launch(void* const* d_in, const int* in_sizes, int n_in,
                              void* d_out, int out_size, void* d_ws, size_t ws_size,
                              hipStream_t stream) {
    const float* pred = (const float*)d_in[0];
    const float* gt = (const float*)d_in[1];
    float* out = (float*)d_out;
    fused_psnr_kernel<<<256, 1024, 0, stream>>>(pred, gt, out);
}

// Round 6
// 145.082 us; speedup vs baseline: 1.0922x; 1.0922x over previous
//
#include <hip/hip_runtime.h>
#include <hip/hip_bf16.h>

#define IMG 128
#define NPIX (IMG * IMG)
#define NT 64
#define LS 129  // padded LDS row stride: col reads (l*LS+c) -> (l+c)%32 banks, 2-way = free

// thr = round_half_even(linspace(2, 90, 64)) -- integer radii
__device__ __constant__ int c_thr[NT] = {
    2, 3, 5, 6, 8, 9, 10, 12, 13, 15, 16, 17, 19, 20, 22, 23,
    24, 26, 27, 29, 30, 31, 33, 34, 36, 37, 38, 40, 41, 43, 44, 45,
    47, 48, 49, 51, 52, 54, 55, 56, 58, 59, 61, 62, 63, 65, 66, 68,
    69, 70, 72, 73, 75, 76, 77, 79, 80, 82, 83, 84, 86, 87, 89, 90};

// 128-point DIF FFT across one wave: lane l holds slots l (a) and l+64 (b).
// Natural-in, bit-reversed-out (slot p holds frequency rev7(p)). No barriers.
__device__ __forceinline__ void fft128(float& ar, float& ai, float& br, float& bi,
                                       const int lane, const float* __restrict__ twc,
                                       const float* __restrict__ tws,
                                       const float w6c, const float w6s) {
    // stage m=64: pair (l, l+64) is lane-local; tw = W^l
    {
        float dr = ar - br, di = ai - bi;
        ar = ar + br; ai = ai + bi;
        br = dr * w6c - di * w6s;
        bi = dr * w6s + di * w6c;
    }
    // stages m=32..1: partner lane = l ^ m, both halves independent
#pragma unroll
    for (int s = 5; s >= 0; --s) {
        const int m = 1 << s;
        const int e = (lane << (6 - s)) & 63;  // = (l & (m-1)) << (6-s)
        const float wc = twc[e], ws = tws[e];
        const float par = __shfl_xor(ar, m, 64);
        const float pai = __shfl_xor(ai, m, 64);
        const float pbr = __shfl_xor(br, m, 64);
        const float pbi = __shfl_xor(bi, m, 64);
        if (lane & m) {
            float dr = par - ar, di = pai - ai;
            ar = dr * wc - di * ws;
            ai = dr * ws + di * wc;
            dr = pbr - br; di = pbi - bi;
            br = dr * wc - di * ws;
            bi = dr * ws + di * wc;
        } else {
            ar += par; ai += pai;
            br += pbr; bi += pbi;
        }
    }
}

// One block (1024 thr = 16 waves) per batch element. Per channel: row FFTs in
// registers (shuffle), stage via LDS, column FFTs in registers, energy histogram
// from registers. Only global writes: 64 output floats per block.
__global__ __launch_bounds__(1024) void fused_psnr_kernel(const float* __restrict__ pred,
                                                          const float* __restrict__ gt,
                                                          float* __restrict__ out) {
    __shared__ float s_re[IMG * LS];   // 64.5 KiB
    __shared__ float s_im[IMG * LS];   // 64.5 KiB
    __shared__ float s_twc[64];
    __shared__ float s_tws[64];
    __shared__ float s_hist[NT];
    __shared__ int s_rc2bin[91];       // integer radius -> first threshold bin

    const int tid = threadIdx.x;
    const int lane = tid & 63;
    const int wave = tid >> 6;
    const int b = blockIdx.x;

    if (tid < 64) {
        float ang = -6.2831853071795864769f * (float)tid * (1.0f / 128.0f);
        float sv, cv;
        sincosf(ang, &sv, &cv);
        s_twc[tid] = cv;
        s_tws[tid] = sv;
        s_hist[tid] = 0.0f;
    }
    if (tid >= 64 && tid < 64 + 91) {
        const int rc = tid - 64;
        int t = 0;
        while (t < 63 && c_thr[t] < rc) ++t;  // smallest t with thr[t] >= rc
        s_rc2bin[rc] = t;
    }

    // per-lane stage-m=64 twiddle W^lane (register-resident, LDS-independent)
    float w6s, w6c;
    sincosf(-6.2831853071795864769f * (float)lane * (1.0f / 128.0f), &w6s, &w6c);

    // per-thread output-row distances: reg a -> stored row `lane`, reg b -> `lane+64`
    // freq(stored p) = rev7(p); rev7(lane+64) = rev7(lane)+1
    const int fa = (int)(__brev((unsigned)lane) >> 25);
    const int fb = fa + 1;
    const int da = (fa < 64) ? fa : 128 - fa;
    const int db = (fb < 64) ? fb : 128 - fb;

    __syncthreads();

    for (int ch = 0; ch < 3; ++ch) {
        const size_t base = ((size_t)b * 3 + ch) * NPIX;

        // ---- row pass: global -> regs -> FFT -> LDS ----
#pragma unroll
        for (int k = 0; k < 8; ++k) {
            const int r = wave * 8 + k;
            const size_t rb = base + (size_t)r * IMG;
            float ar = pred[rb + lane] - gt[rb + lane];
            float br = pred[rb + lane + 64] - gt[rb + lane + 64];
            float ai = 0.0f, bi = 0.0f;
            fft128(ar, ai, br, bi, lane, s_twc, s_tws, w6c, w6s);
            s_re[r * LS + lane] = ar;
            s_im[r * LS + lane] = ai;
            s_re[r * LS + lane + 64] = br;
            s_im[r * LS + lane + 64] = bi;
        }
        __syncthreads();

        // ---- column pass: LDS -> regs -> FFT -> histogram (no write-back) ----
#pragma unroll
        for (int k = 0; k < 8; ++k) {
            const int c = wave * 8 + k;
            float ar = s_re[lane * LS + c];
            float ai = s_im[lane * LS + c];
            float br = s_re[(lane + 64) * LS + c];
            float bi = s_im[(lane + 64) * LS + c];
            fft128(ar, ai, br, bi, lane, s_twc, s_tws, w6c, w6s);

            const int g = (int)(__brev((unsigned)c) >> 25);
            const int dx = (g < 64) ? g : 128 - g;
            const int dx2 = dx * dx;

            const int r2a = da * da + dx2;
            if (r2a <= 8100) {
                const int rc = (int)ceilf(sqrtf((float)r2a) - 3e-4f);
                atomicAdd(&s_hist[s_rc2bin[rc]], ar * ar + ai * ai);
            }
            const int r2b = db * db + dx2;
            if (r2b <= 8100) {
                const int rc = (int)ceilf(sqrtf((float)r2b) - 3e-4f);
                atomicAdd(&s_hist[s_rc2bin[rc]], br * br + bi * bi);
            }
        }
        __syncthreads();  // hist done; s_re/s_im free for next channel
    }

    // ---- inclusive prefix over bins, PSNR ----
    if (tid < 64) {
        float cum = 0.0f;
        for (int j = 0; j <= tid; ++j) cum += s_hist[j];
        out[b * NT + tid] = 84.2883987849f - 10.0f * log10f(cum);  // 20*log10(16384) - 10*log10(cum)
    }
}

extern "C" void kernel_launch(void* const* d_in, const int* in_sizes, int n_in,
                              void* d_out, int out_size, void* d_ws, size_t ws_size,
                              hipStream_t stream) {
    const float* pred = (const float*)d_in[0];
    const float* gt = (const float*)d_in[1];
    float* out = (float*)d_out;
    fused_psnr_kernel<<<256, 1024, 0, stream>>>(pred, gt, out);
}

// Round 7
// 69.995 us; speedup vs baseline: 2.2640x; 2.0728x over previous
//
#include <hip/hip_runtime.h>
#include <hip/hip_fp16.h>

#define IMG 128
#define NPIX (IMG * IMG)
#define NT 64
#define LSU 129          // u32 row stride of Z staging (129 % 32 == 1)
#define ZCH (64 * LSU)   // u32s per channel of Z staging

// thr = round_half_even(linspace(2, 90, 64))
__device__ __constant__ int c_thr[NT] = {
    2, 3, 5, 6, 8, 9, 10, 12, 13, 15, 16, 17, 19, 20, 22, 23,
    24, 26, 27, 29, 30, 31, 33, 34, 36, 37, 38, 40, 41, 43, 44, 45,
    47, 48, 49, 51, 52, 54, 55, 56, 58, 59, 61, 62, 63, 65, 66, 68,
    69, 70, 72, 73, 75, 76, 77, 79, 80, 82, 83, 84, 86, 87, 89, 90};

__device__ __forceinline__ int rev7(int x) { return (int)(__brev((unsigned)x) >> 25); }

__device__ __forceinline__ unsigned packh2(float x, float y) {
    __half2 h = __floats2half2_rn(x, y);
    return *reinterpret_cast<unsigned*>(&h);
}
__device__ __forceinline__ float2 unpackh2(unsigned u) {
    __half2 h;
    *reinterpret_cast<unsigned*>(&h) = u;
    return __half22float2(h);
}

// Per-lane FFT twiddles, all register-resident (no LDS reads inside the FFT).
// c6/s6: stage m=64 twiddle W^lane. c[s]/s[s]: effective twiddle for shuffle
// stage m=2^s with the low-lane identity (1,0) folded in; sg[s] = -1 on hi lanes.
struct Tw {
    float c[6], s[6], sg[6];
    float c6, s6;
};

// 128-pt DIF FFT across one wave: lane l holds slots l (a) and l+64 (b).
// Natural-order in, bit-reversed out (slot p holds frequency rev7(p)). Branchless.
__device__ __forceinline__ void fft128(float& ar, float& ai, float& br, float& bi,
                                       const Tw& tw) {
    // stage m=64: lane-local
    {
        float dr = ar - br, di = ai - bi;
        ar += br; ai += bi;
        br = dr * tw.c6 - di * tw.s6;
        bi = dr * tw.s6 + di * tw.c6;
    }
    // stages m=32..1: partner = lane ^ m
#pragma unroll
    for (int s = 5; s >= 0; --s) {
        const int m = 1 << s;
        const float wc = tw.c[s], ws = tw.s[s], sg = tw.sg[s];
        const float par = __shfl_xor(ar, m, 64);
        const float pai = __shfl_xor(ai, m, 64);
        const float pbr = __shfl_xor(br, m, 64);
        const float pbi = __shfl_xor(bi, m, 64);
        float xr = fmaf(sg, ar, par), xi = fmaf(sg, ai, pai);
        ar = xr * wc - xi * ws;
        ai = xr * ws + xi * wc;
        xr = fmaf(sg, br, pbr);
        xi = fmaf(sg, bi, pbi);
        br = xr * wc - xi * ws;
        bi = xr * ws + xi * wc;
    }
}

// One block (16 waves) per batch element b. Real-input 2D FFT via row-pair
// packing: 64 packed row FFTs/channel -> Z staged in LDS as fp16x2; column
// FFTs only u=0..64 (Hermitian mirror = weight 2 in the radial histogram).
// Only global writes: the 64 output floats.
__global__ __launch_bounds__(1024) void fused_psnr_kernel(const float* __restrict__ pred,
                                                          const float* __restrict__ gt,
                                                          float* __restrict__ out) {
    __shared__ unsigned s_z[3 * ZCH];  // 3 ch x 64 rows x 129 u32 (fp16x2) = 96.8 KiB
    __shared__ float s_hist[NT];
    __shared__ int s_rc2bin[91];

    const int tid = threadIdx.x;
    const int lane = tid & 63;
    const int wave = tid >> 6;  // 0..15
    const int b = blockIdx.x;

    if (tid < 64) s_hist[tid] = 0.0f;
    if (tid >= 64 && tid < 64 + 91) {
        const int rc = tid - 64;
        int t = 0;
        while (t < 63 && c_thr[t] < rc) ++t;  // smallest t with thr[t] >= rc
        s_rc2bin[rc] = t;
    }

    // register-resident twiddles
    Tw tw;
    const float K = -6.2831853071795864769f * (1.0f / 128.0f);
    sincosf(K * (float)lane, &tw.s6, &tw.c6);
#pragma unroll
    for (int s = 0; s < 6; ++s) {
        const int m = 1 << s;
        const bool hi = (lane & m) != 0;
        const int e = (lane << (6 - s)) & 63;
        float sv, cv;
        sincosf(K * (float)e, &sv, &cv);
        tw.c[s] = hi ? cv : 1.0f;
        tw.s[s] = hi ? sv : 0.0f;
        tw.sg[s] = hi ? -1.0f : 1.0f;
    }

    // per-lane frequency rows for histogram: slot a -> v=rev7(lane), slot b -> v+1
    const int fa = rev7(lane);
    const int da = (fa < 64) ? fa : 128 - fa;
    const int fb = fa + 1;
    const int db = (fb < 64) ? fb : 128 - fb;

    const size_t ibase = (size_t)b * 3 * NPIX;

    // ---- row pass: 192 packed row-FFTs (ch,r): z = 0.5*(d(2r,.) + i d(2r+1,.)) ----
#pragma unroll 2
    for (int k = 0; k < 12; ++k) {
        const int id = k * 16 + wave;  // 0..191
        const int ch = id >> 6;
        const int r = id & 63;
        const float* p0 = pred + ibase + (size_t)ch * NPIX + (size_t)(2 * r) * IMG;
        const float* g0 = gt + ibase + (size_t)ch * NPIX + (size_t)(2 * r) * IMG;
        float ar = 0.5f * (p0[lane] - g0[lane]);
        float br = 0.5f * (p0[lane + 64] - g0[lane + 64]);
        float ai = 0.5f * (p0[IMG + lane] - g0[IMG + lane]);
        float bi = 0.5f * (p0[IMG + lane + 64] - g0[IMG + lane + 64]);
        fft128(ar, ai, br, bi, tw);
        const int zb = ch * ZCH + r * LSU;
        s_z[zb + lane] = packh2(ar, ai);
        s_z[zb + lane + 64] = packh2(br, bi);
    }
    __syncthreads();

    // ---- column pass: 195 column-FFTs (ch, u=0..64) + histogram ----
    const int r1 = lane >> 1;       // Z row for slot a (y = lane)
    const int r2 = r1 + 32;         // Z row for slot b (y = lane+64)
    const int odd = lane & 1;
#pragma unroll 2
    for (int k = 0; k < 13; ++k) {
        const int id = k * 16 + wave;
        if (id < 195) {
            const int ch = id / 65;
            const int u = id - ch * 65;              // 0..64
            const int c1 = rev7(u);                  // stored col of freq u
            const int c2 = rev7((128 - u) & 127);    // stored col of freq -u
            const int zb = ch * ZCH;
            const float2 a1 = unpackh2(s_z[zb + r1 * LSU + c1]);
            const float2 b1 = unpackh2(s_z[zb + r1 * LSU + c2]);
            const float2 a2 = unpackh2(s_z[zb + r2 * LSU + c1]);
            const float2 b2 = unpackh2(s_z[zb + r2 * LSU + c2]);
            // unpack: even y: G = A + conj(B); odd y: G = -i(A - conj(B))
            float ar = odd ? (a1.y + b1.y) : (a1.x + b1.x);
            float ai = odd ? (b1.x - a1.x) : (a1.y - b1.y);
            float br = odd ? (a2.y + b2.y) : (a2.x + b2.x);
            float bi = odd ? (b2.x - a2.x) : (a2.y - b2.y);
            fft128(ar, ai, br, bi, tw);

            const float wf = (u == 0 || u == 64) ? 1.0f : 2.0f;  // Hermitian mirror weight
            const int du2 = u * u;
            const int r2a = da * da + du2;
            if (r2a <= 8100) {
                const int rc = (int)ceilf(sqrtf((float)r2a) - 3e-4f);
                atomicAdd(&s_hist[s_rc2bin[rc]], wf * (ar * ar + ai * ai));
            }
            const int r2b = db * db + du2;
            if (r2b <= 8100) {
                const int rc = (int)ceilf(sqrtf((float)r2b) - 3e-4f);
                atomicAdd(&s_hist[s_rc2bin[rc]], wf * (br * br + bi * bi));
            }
        }
    }
    __syncthreads();

    // ---- inclusive prefix over bins, PSNR ----
    if (tid < 64) {
        float cum = 0.0f;
        for (int j = 0; j <= tid; ++j) cum += s_hist[j];
        out[b * NT + tid] = 84.2883987849f - 10.0f * log10f(cum);  // 20*log10(16384) - 10*log10(cum)
    }
}

extern "C" void kernel_launch(void* const* d_in, const int* in_sizes, int n_in,
                              void* d_out, int out_size, void* d_ws, size_t ws_size,
                              hipStream_t stream) {
    const float* pred = (const float*)d_in[0];
    const float* gt = (const float*)d_in[1];
    float* out = (float*)d_out;
    fused_psnr_kernel<<<256, 1024, 0, stream>>>(pred, gt, out);
}

// Round 8
// 58.064 us; speedup vs baseline: 2.7291x; 1.2055x over previous
//
#include <hip/hip_runtime.h>
#include <hip/hip_fp16.h>

#define IMG 128
#define NPIX (IMG * IMG)
#define NT 64
#define LSU 129          // u32 row stride of Z staging (129 % 32 == 1)
#define ZCH (64 * LSU)   // u32s per channel

// thr = round_half_even(linspace(2, 90, 64))
__device__ __constant__ int c_thr[NT] = {
    2, 3, 5, 6, 8, 9, 10, 12, 13, 15, 16, 17, 19, 20, 22, 23,
    24, 26, 27, 29, 30, 31, 33, 34, 36, 37, 38, 40, 41, 43, 44, 45,
    47, 48, 49, 51, 52, 54, 55, 56, 58, 59, 61, 62, 63, 65, 66, 68,
    69, 70, 72, 73, 75, 76, 77, 79, 80, 82, 83, 84, 86, 87, 89, 90};

__device__ __forceinline__ int rev7(int x) { return (int)(__brev((unsigned)x) >> 25); }

__device__ __forceinline__ unsigned packh2(float x, float y) {
    __half2 h = __floats2half2_rn(x, y);
    return *reinterpret_cast<unsigned*>(&h);
}
__device__ __forceinline__ float2 unpackh2(unsigned u) {
    __half2 h;
    *reinterpret_cast<unsigned*>(&h) = u;
    return __half22float2(h);
}

// cross-lane pulls: DPP (VALU pipe) where possible, ds_swizzle only for xor-4
__device__ __forceinline__ float x1f(float v) {  // lane^1: quad_perm [1,0,3,2]
    return __int_as_float(__builtin_amdgcn_mov_dpp(__float_as_int(v), 0xB1, 0xF, 0xF, true));
}
__device__ __forceinline__ float x2f(float v) {  // lane^2: quad_perm [2,3,0,1]
    return __int_as_float(__builtin_amdgcn_mov_dpp(__float_as_int(v), 0x4E, 0xF, 0xF, true));
}
__device__ __forceinline__ float x4f(float v) {  // lane^4: ds_swizzle xor-mask 4
    return __int_as_float(__builtin_amdgcn_ds_swizzle(__float_as_int(v), 0x101F));
}
__device__ __forceinline__ float x8f(float v) {  // lane^8: row_ror:8 (16-lane rows)
    return __int_as_float(__builtin_amdgcn_mov_dpp(__float_as_int(v), 0x128, 0xF, 0xF, true));
}

// One block (16 waves) per batch element. Each 16-lane group owns one 128-pt
// FFT: lane l holds 8 complex values at slots 16j+l. Stages m=64/32/16 are
// lane-local VALU; m=8/2/1 via DPP; only m=4 touches the DS pipe. Natural-order
// in, bit-reversed out. Row-pair Hermitian packing as in round 7.
__global__ __launch_bounds__(1024) void fused_psnr_kernel(const float* __restrict__ pred,
                                                          const float* __restrict__ gt,
                                                          float* __restrict__ out) {
    __shared__ unsigned s_z[3 * ZCH];  // 96.75 KiB fp16x2 Z staging
    __shared__ float s_hist[NT];
    __shared__ int s_rc2bin[91];

    const int tid = threadIdx.x;
    const int lane = tid & 63;
    const int wave = tid >> 6;   // 0..15
    const int l = lane & 15;     // position within 16-lane FFT group
    const int g = lane >> 4;     // group 0..3 within wave
    const int b = blockIdx.x;

    if (tid < 64) s_hist[tid] = 0.0f;
    if (tid >= 64 && tid < 64 + 91) {
        const int rc = tid - 64;
        int t = 0;
        while (t < 63 && c_thr[t] < rc) ++t;
        s_rc2bin[rc] = t;
    }

    // ---- register-resident twiddles (W = exp(-2*pi*i/128)) ----
    const float K = -6.2831853071795864769f * (1.0f / 128.0f);
    float c64[4], s64[4], c32[2], s32[2], c16v, s16v;
#pragma unroll
    for (int j = 0; j < 4; ++j) sincosf(K * (float)(16 * j + l), &s64[j], &c64[j]);
    sincosf(K * (float)(2 * l), &s32[0], &c32[0]);
    sincosf(K * (float)(2 * l + 32), &s32[1], &c32[1]);
    sincosf(K * (float)(4 * l), &s16v, &c16v);
    float c8v, s8v, c4v, s4v, c2v, s2v;
    sincosf(K * (float)((l & 8) ? (l & 7) * 8 : 0), &s8v, &c8v);
    sincosf(K * (float)((l & 4) ? (l & 3) * 16 : 0), &s4v, &c4v);
    sincosf(K * (float)((l & 2) ? (l & 1) * 32 : 0), &s2v, &c2v);
    const float sg8 = (l & 8) ? -1.0f : 1.0f;
    const float sg4 = (l & 4) ? -1.0f : 1.0f;
    const float sg2 = (l & 2) ? -1.0f : 1.0f;
    const float sg1 = (l & 1) ? -1.0f : 1.0f;

    // per-(lane,j) row-frequency distance^2: slot p=16j+l holds freq rev7(p)
    float dy2f[8];
    const int r4 = ((l & 1) << 3) | ((l & 2) << 1) | ((l & 4) >> 1) | ((l & 8) >> 3);
#pragma unroll
    for (int j = 0; j < 8; ++j) {
        const int fy = (((j & 1) << 2) | (j & 2) | ((j & 4) >> 2)) | (r4 << 3);
        const int dy = (fy < 64) ? fy : 128 - fy;
        dy2f[j] = (float)(dy * dy);
    }

    // lane-local DIF butterfly: (a,b) -> (a+b, (a-b)*w)
    auto bfly = [](float& ar, float& ai, float& br, float& bi, float wc, float wsn) {
        const float dr = ar - br, di = ai - bi;
        ar += br; ai += bi;
        br = dr * wc - di * wsn;
        bi = dr * wsn + di * wc;
    };

    // full 128-pt FFT on this group's 8 values/lane
    auto fft = [&](float* vr, float* vi) {
        // m=64: (j, j+4), tw = W^(16j+l)
#pragma unroll
        for (int j = 0; j < 4; ++j) bfly(vr[j], vi[j], vr[j + 4], vi[j + 4], c64[j], s64[j]);
        // m=32: (j, j+2) for j in {0,1,4,5}, tw = W^(32*(j&1)+2l)
        bfly(vr[0], vi[0], vr[2], vi[2], c32[0], s32[0]);
        bfly(vr[1], vi[1], vr[3], vi[3], c32[1], s32[1]);
        bfly(vr[4], vi[4], vr[6], vi[6], c32[0], s32[0]);
        bfly(vr[5], vi[5], vr[7], vi[7], c32[1], s32[1]);
        // m=16: (j, j+1) for even j, tw = W^(4l)
#pragma unroll
        for (int j = 0; j < 8; j += 2) bfly(vr[j], vi[j], vr[j + 1], vi[j + 1], c16v, s16v);
        // m=8: lane^8 (DPP), folded tw
#pragma unroll
        for (int j = 0; j < 8; ++j) {
            const float pr = x8f(vr[j]), pi = x8f(vi[j]);
            const float xr = fmaf(sg8, vr[j], pr), xi = fmaf(sg8, vi[j], pi);
            vr[j] = xr * c8v - xi * s8v;
            vi[j] = xr * s8v + xi * c8v;
        }
        // m=4: lane^4 (ds_swizzle), folded tw
#pragma unroll
        for (int j = 0; j < 8; ++j) {
            const float pr = x4f(vr[j]), pi = x4f(vi[j]);
            const float xr = fmaf(sg4, vr[j], pr), xi = fmaf(sg4, vi[j], pi);
            vr[j] = xr * c4v - xi * s4v;
            vi[j] = xr * s4v + xi * c4v;
        }
        // m=2: lane^2 (DPP), folded tw
#pragma unroll
        for (int j = 0; j < 8; ++j) {
            const float pr = x2f(vr[j]), pi = x2f(vi[j]);
            const float xr = fmaf(sg2, vr[j], pr), xi = fmaf(sg2, vi[j], pi);
            vr[j] = xr * c2v - xi * s2v;
            vi[j] = xr * s2v + xi * c2v;
        }
        // m=1: lane^1 (DPP), tw = 1
#pragma unroll
        for (int j = 0; j < 8; ++j) {
            const float pr = x1f(vr[j]), pi = x1f(vi[j]);
            vr[j] = fmaf(sg1, vr[j], pr);
            vi[j] = fmaf(sg1, vi[j], pi);
        }
    };

    const size_t ibase = (size_t)b * 3 * NPIX;

    // ---- row pass: 48 batches of 4 packed row-FFTs; groups take rows q+8g ----
    for (int t3 = 0; t3 < 3; ++t3) {
        const int T = t3 * 16 + wave;          // 0..47
        const int ch = T >> 4;
        const int Bp = T & 15;
        const int q = (Bp & 7) | ((Bp >> 3) << 5);
        const int r = q + 8 * g;               // 0..63
        const float* pe = pred + ibase + (size_t)ch * NPIX + (size_t)(2 * r) * IMG;
        const float* ge = gt + ibase + (size_t)ch * NPIX + (size_t)(2 * r) * IMG;
        float vr[8], vi[8];
#pragma unroll
        for (int j = 0; j < 8; ++j) {
            const int o = 16 * j + l;
            vr[j] = 0.5f * (pe[o] - ge[o]);            // row 2r
            vi[j] = 0.5f * (pe[IMG + o] - ge[IMG + o]); // row 2r+1
        }
        fft(vr, vi);
        const int zb = ch * ZCH + r * LSU;
#pragma unroll
        for (int j = 0; j < 8; ++j) s_z[zb + 16 * j + l] = packh2(vr[j], vi[j]);
    }
    __syncthreads();

    // ---- col pass: 51 batches (3 ch x 17); groups take u = v+4g (t<16), u=64 (t=16) ----
    for (int t3 = 0; t3 < 4; ++t3) {
        const int T = t3 * 16 + wave;
        if (T >= 51) break;                    // wave-uniform
        const int ch = T / 17;
        const int t = T - ch * 17;
        int u;
        float wf;
        if (t < 16) {
            u = (t & 3) + ((t >> 2) << 4) + 4 * g;   // covers 0..63
            wf = (u == 0) ? 1.0f : 2.0f;             // Hermitian mirror weight
        } else {
            u = 64;
            wf = (g == 0) ? 1.0f : 0.0f;             // dedupe: only group 0 counts
        }
        const int c1 = rev7(u);
        const int c2 = rev7((128 - u) & 127);
        const int zb = ch * ZCH;
        const int zr = l >> 1;
        const int odd = l & 1;
        float vr[8], vi[8];
#pragma unroll
        for (int j = 0; j < 8; ++j) {
            const int rowo = zb + (8 * j + zr) * LSU;
            const float2 A = unpackh2(s_z[rowo + c1]);
            const float2 B = unpackh2(s_z[rowo + c2]);
            // y = 16j+l; even y: G = A + conj(B); odd y: G = -i(A - conj(B))
            vr[j] = odd ? (A.y + B.y) : (A.x + B.x);
            vi[j] = odd ? (B.x - A.x) : (A.y - B.y);
        }
        fft(vr, vi);
        const float u2f = (float)(u * u);
#pragma unroll
        for (int j = 0; j < 8; ++j) {
            const float r2f = dy2f[j] + u2f;
            if (wf != 0.0f && r2f <= 8100.0f) {
                const int rc = (int)ceilf(sqrtf(r2f) - 3e-4f);
                atomicAdd(&s_hist[s_rc2bin[rc]], wf * (vr[j] * vr[j] + vi[j] * vi[j]));
            }
        }
    }
    __syncthreads();

    // ---- inclusive prefix over bins, PSNR ----
    if (tid < 64) {
        float cum = 0.0f;
        for (int j = 0; j <= tid; ++j) cum += s_hist[j];
        out[b * NT + tid] = 84.2883987849f - 10.0f * log10f(cum);  // 20*log10(16384) - 10*log10(cum)
    }
}

extern "C" void kernel_launch(void* const* d_in, const int* in_sizes, int n_in,
                              void* d_out, int out_size, void* d_ws, size_t ws_size,
                              hipStream_t stream) {
    const float* pred = (const float*)d_in[0];
    const float* gt = (const float*)d_in[1];
    float* out = (float*)d_out;
    fused_psnr_kernel<<<256, 1024, 0, stream>>>(pred, gt, out);
}

// Round 9
// 58.028 us; speedup vs baseline: 2.7308x; 1.0006x over previous
//
#include <hip/hip_runtime.h>
#include <hip/hip_fp16.h>

#define IMG 128
#define NPIX (IMG * IMG)
#define NT 64
#define LSU 129          // u32 row stride of Z staging (129 % 32 == 1)
#define ZCH (64 * LSU)   // u32s per channel

// thr = round_half_even(linspace(2, 90, 64))
__device__ __constant__ int c_thr[NT] = {
    2, 3, 5, 6, 8, 9, 10, 12, 13, 15, 16, 17, 19, 20, 22, 23,
    24, 26, 27, 29, 30, 31, 33, 34, 36, 37, 38, 40, 41, 43, 44, 45,
    47, 48, 49, 51, 52, 54, 55, 56, 58, 59, 61, 62, 63, 65, 66, 68,
    69, 70, 72, 73, 75, 76, 77, 79, 80, 82, 83, 84, 86, 87, 89, 90};

__device__ __forceinline__ int rev7(int x) { return (int)(__brev((unsigned)x) >> 25); }

__device__ __forceinline__ unsigned packh2(float x, float y) {
    __half2 h = __floats2half2_rn(x, y);
    return *reinterpret_cast<unsigned*>(&h);
}
__device__ __forceinline__ float2 unpackh2(unsigned u) {
    __half2 h;
    *reinterpret_cast<unsigned*>(&h) = u;
    return __half22float2(h);
}

// cross-lane pulls -- ALL on the VALU pipe (DPP), zero DS ops in the FFT
__device__ __forceinline__ float x1f(float v) {  // lane^1: quad_perm [1,0,3,2]
    return __int_as_float(__builtin_amdgcn_mov_dpp(__float_as_int(v), 0xB1, 0xF, 0xF, true));
}
__device__ __forceinline__ float x2f(float v) {  // lane^2: quad_perm [2,3,0,1]
    return __int_as_float(__builtin_amdgcn_mov_dpp(__float_as_int(v), 0x4E, 0xF, 0xF, true));
}
__device__ __forceinline__ float x3f(float v) {  // lane^3: quad_perm [3,2,1,0]
    return __int_as_float(__builtin_amdgcn_mov_dpp(__float_as_int(v), 0x1B, 0xF, 0xF, true));
}
__device__ __forceinline__ float x7f(float v) {  // lane^7: row_half_mirror
    return __int_as_float(__builtin_amdgcn_mov_dpp(__float_as_int(v), 0x141, 0xF, 0xF, true));
}
__device__ __forceinline__ float x4f(float v) {  // lane^4 = (lane^3)^7, two DPP movs
    return x7f(x3f(v));
}
__device__ __forceinline__ float x8f(float v) {  // lane^8: row_ror:8
    return __int_as_float(__builtin_amdgcn_mov_dpp(__float_as_int(v), 0x128, 0xF, 0xF, true));
}

// One block (16 waves) per batch element. Each 16-lane group owns one 128-pt
// FFT: lane l holds 8 complex values at slots 16j+l. Stages m=64/32/16 are
// lane-local VALU; m=8/4/2/1 via DPP. Natural-order in, bit-reversed out.
// Row-pair Hermitian packing; fp16x2 Z staging; per-wave histograms.
__global__ __launch_bounds__(1024) void fused_psnr_kernel(const float* __restrict__ pred,
                                                          const float* __restrict__ gt,
                                                          float* __restrict__ out) {
    __shared__ unsigned s_z[3 * ZCH];   // 96.75 KiB fp16x2 Z staging
    __shared__ float s_h[16][66];       // per-wave hist, padded stride
    __shared__ int s_rc2bin[91];

    const int tid = threadIdx.x;
    const int lane = tid & 63;
    const int wave = tid >> 6;   // 0..15
    const int l = lane & 15;     // position within 16-lane FFT group
    const int g = lane >> 4;     // group 0..3 within wave
    const int b = blockIdx.x;

    for (int i = tid; i < 16 * 66; i += 1024) (&s_h[0][0])[i] = 0.0f;
    if (tid < 91) {
        int t = 0;
        while (t < 63 && c_thr[t] < tid) ++t;  // smallest t with thr[t] >= radius
        s_rc2bin[tid] = t;
    }

    // ---- register-resident twiddles (W = exp(-2*pi*i/128)) ----
    const float K = -6.2831853071795864769f * (1.0f / 128.0f);
    float c64[4], s64[4], c32[2], s32[2], c16v, s16v;
#pragma unroll
    for (int j = 0; j < 4; ++j) sincosf(K * (float)(16 * j + l), &s64[j], &c64[j]);
    sincosf(K * (float)(2 * l), &s32[0], &c32[0]);
    sincosf(K * (float)(2 * l + 32), &s32[1], &c32[1]);
    sincosf(K * (float)(4 * l), &s16v, &c16v);
    float c8v, s8v, c4v, s4v, c2v, s2v;
    sincosf(K * (float)((l & 8) ? (l & 7) * 8 : 0), &s8v, &c8v);
    sincosf(K * (float)((l & 4) ? (l & 3) * 16 : 0), &s4v, &c4v);
    sincosf(K * (float)((l & 2) ? (l & 1) * 32 : 0), &s2v, &c2v);
    const float sg8 = (l & 8) ? -1.0f : 1.0f;
    const float sg4 = (l & 4) ? -1.0f : 1.0f;
    const float sg2 = (l & 2) ? -1.0f : 1.0f;
    const float sg1 = (l & 1) ? -1.0f : 1.0f;

    auto bfly = [](float& ar, float& ai, float& br, float& bi, float wc, float wsn) {
        const float dr = ar - br, di = ai - bi;
        ar += br; ai += bi;
        br = dr * wc - di * wsn;
        bi = dr * wsn + di * wc;
    };

    auto fft = [&](float* vr, float* vi) {
#pragma unroll
        for (int j = 0; j < 4; ++j) bfly(vr[j], vi[j], vr[j + 4], vi[j + 4], c64[j], s64[j]);
        bfly(vr[0], vi[0], vr[2], vi[2], c32[0], s32[0]);
        bfly(vr[1], vi[1], vr[3], vi[3], c32[1], s32[1]);
        bfly(vr[4], vi[4], vr[6], vi[6], c32[0], s32[0]);
        bfly(vr[5], vi[5], vr[7], vi[7], c32[1], s32[1]);
#pragma unroll
        for (int j = 0; j < 8; j += 2) bfly(vr[j], vi[j], vr[j + 1], vi[j + 1], c16v, s16v);
#pragma unroll
        for (int j = 0; j < 8; ++j) {  // m=8 (DPP row_ror:8)
            const float pr = x8f(vr[j]), pi = x8f(vi[j]);
            const float xr = fmaf(sg8, vr[j], pr), xi = fmaf(sg8, vi[j], pi);
            vr[j] = xr * c8v - xi * s8v;
            vi[j] = xr * s8v + xi * c8v;
        }
#pragma unroll
        for (int j = 0; j < 8; ++j) {  // m=4 (two DPP movs, no DS)
            const float pr = x4f(vr[j]), pi = x4f(vi[j]);
            const float xr = fmaf(sg4, vr[j], pr), xi = fmaf(sg4, vi[j], pi);
            vr[j] = xr * c4v - xi * s4v;
            vi[j] = xr * s4v + xi * c4v;
        }
#pragma unroll
        for (int j = 0; j < 8; ++j) {  // m=2 (DPP)
            const float pr = x2f(vr[j]), pi = x2f(vi[j]);
            const float xr = fmaf(sg2, vr[j], pr), xi = fmaf(sg2, vi[j], pi);
            vr[j] = xr * c2v - xi * s2v;
            vi[j] = xr * s2v + xi * c2v;
        }
#pragma unroll
        for (int j = 0; j < 8; ++j) {  // m=1 (DPP), tw = 1
            const float pr = x1f(vr[j]), pi = x1f(vi[j]);
            vr[j] = fmaf(sg1, vr[j], pr);
            vi[j] = fmaf(sg1, vi[j], pi);
        }
    };

    const size_t ibase = (size_t)b * 3 * NPIX;

    // ---- row pass: 48 wave-iters, software-pipelined global loads ----
    auto ldRow = [&](int T, float* buf) {
        const int ch = T >> 4;
        const int Bp = T & 15;
        const int q = (Bp & 7) | ((Bp >> 3) << 5);
        const int r = q + 8 * g;
        const float* pe = pred + ibase + (size_t)ch * NPIX + (size_t)(2 * r) * IMG;
        const float* ge = gt + ibase + (size_t)ch * NPIX + (size_t)(2 * r) * IMG;
#pragma unroll
        for (int j = 0; j < 8; ++j) {
            const int o = 16 * j + l;
            buf[j] = pe[o];
            buf[8 + j] = pe[IMG + o];
            buf[16 + j] = ge[o];
            buf[24 + j] = ge[IMG + o];
        }
    };
    auto doRow = [&](int T, const float* buf) {
        const int ch = T >> 4;
        const int Bp = T & 15;
        const int q = (Bp & 7) | ((Bp >> 3) << 5);
        const int r = q + 8 * g;
        float vr[8], vi[8];
#pragma unroll
        for (int j = 0; j < 8; ++j) {
            vr[j] = 0.5f * (buf[j] - buf[16 + j]);
            vi[j] = 0.5f * (buf[8 + j] - buf[24 + j]);
        }
        fft(vr, vi);
        const int zb = ch * ZCH + r * LSU;
#pragma unroll
        for (int j = 0; j < 8; ++j) s_z[zb + 16 * j + l] = packh2(vr[j], vi[j]);
    };

    {
        float bufA[32], bufB[32];
        ldRow(wave, bufA);
        ldRow(16 + wave, bufB);   // in flight while FFT(A) runs
        doRow(wave, bufA);
        ldRow(32 + wave, bufA);
        doRow(16 + wave, bufB);
        doRow(32 + wave, bufA);
    }
    __syncthreads();

    // per-(lane,j) row-frequency distance^2 (needed only in col pass; computed
    // here to keep row-pass VGPR peak under the 16-wave 128-reg ceiling)
    float dy2f[8];
    const int r4 = ((l & 1) << 3) | ((l & 2) << 1) | ((l & 4) >> 1) | ((l & 8) >> 3);
#pragma unroll
    for (int j = 0; j < 8; ++j) {
        const int fy = (((j & 1) << 2) | (j & 2) | ((j & 4) >> 2)) | (r4 << 3);
        const int dy = (fy < 64) ? fy : 128 - fy;
        dy2f[j] = (float)(dy * dy);
    }
    const int zr = l >> 1;
    const int odd = l & 1;

    // ---- col pass: T in {wave, wave+16, wave+32, wave+48<51}, pipelined ----
    auto ldZf = [&](int T, unsigned* raw) {
        const int ch = T / 17;
        const int t = T - ch * 17;
        const int u = (t < 16) ? ((t & 3) + ((t >> 2) << 4) + 4 * g) : 64;
        const int c1 = rev7(u);
        const int c2 = rev7((128 - u) & 127);
        const int zb = ch * ZCH;
#pragma unroll
        for (int j = 0; j < 8; ++j) {
            const int rowo = zb + (8 * j + zr) * LSU;
            raw[2 * j] = s_z[rowo + c1];
            raw[2 * j + 1] = s_z[rowo + c2];
        }
    };
    auto doCol = [&](int T, const unsigned* raw) {
        const int ch = T / 17;
        const int t = T - ch * 17;
        int u;
        float wf;
        if (t < 16) {
            u = (t & 3) + ((t >> 2) << 4) + 4 * g;
            wf = (u == 0) ? 1.0f : 2.0f;            // Hermitian mirror weight
        } else {
            u = 64;
            wf = (g == 0) ? 1.0f : 0.0f;            // dedupe u=64 across groups
        }
        float vr[8], vi[8];
#pragma unroll
        for (int j = 0; j < 8; ++j) {
            const float2 A = unpackh2(raw[2 * j]);
            const float2 B = unpackh2(raw[2 * j + 1]);
            // y = 16j+l; even y: G = A + conj(B); odd y: G = -i(A - conj(B))
            vr[j] = odd ? (A.y + B.y) : (A.x + B.x);
            vi[j] = odd ? (B.x - A.x) : (A.y - B.y);
        }
        fft(vr, vi);
        const float u2f = (float)(u * u);
#pragma unroll
        for (int j = 0; j < 8; ++j) {
            const float r2f = dy2f[j] + u2f;
            if (wf != 0.0f && r2f <= 8100.0f) {
                const int rc = (int)ceilf(sqrtf(r2f) - 3e-4f);
                atomicAdd(&s_h[wave][s_rc2bin[rc]], wf * (vr[j] * vr[j] + vi[j] * vi[j]));
            }
        }
    };

    {
        unsigned zA[16], zB[16];
        ldZf(wave, zA);
        ldZf(wave + 16, zB);
        doCol(wave, zA);
        ldZf(wave + 32, zA);
        doCol(wave + 16, zB);
        if (wave + 48 < 51) ldZf(wave + 48, zB);
        doCol(wave + 32, zA);
        if (wave + 48 < 51) doCol(wave + 48, zB);
    }
    __syncthreads();

    // ---- combine 16 wave-hists, inclusive prefix, PSNR (wave 0 only) ----
    if (tid < 64) {
        float tot = 0.0f;
#pragma unroll
        for (int w = 0; w < 16; ++w) tot += s_h[w][tid];
        s_h[0][tid] = tot;   // same-wave LDS ordering: store before loads below
        float cum = 0.0f;
        for (int j = 0; j <= tid; ++j) cum += s_h[0][j];
        out[b * NT + tid] = 84.2883987849f - 10.0f * log10f(cum);  // 20*log10(16384) - 10*log10(cum)
    }
}

extern "C" void kernel_launch(void* const* d_in, const int* in_sizes, int n_in,
                              void* d_out, int out_size, void* d_ws, size_t ws_size,
                              hipStream_t stream) {
    const float* pred = (const float*)d_in[0];
    const float* gt = (const float*)d_in[1];
    float* out = (float*)d_out;
    fused_psnr_kernel<<<256, 1024, 0, stream>>>(pred, gt, out);
}